// Round 8
// baseline (194.675 us; speedup 1.0000x reference)
//
#include <hip/hip_runtime.h>
#include <hip/hip_cooperative_groups.h>

namespace cg = cooperative_groups;

// Rotated NMS, N boxes [xc,yc,w,h,theta_deg], scores. Output: first 1000 kept
// original indices in score-sorted order, -1 padded. IoU math replicates the
// reference's float32 op order (contract off) — rounds 1-7: absmax 0.
//
// Round 8: all 5 phases fused into ONE cooperative dispatch (round-7 profile:
// every kernel <15 us; 5 dependent launches' overhead dominated).

#define WL_LDS_CAP 4096
#define WL_G_CAP 65536
#define FG 256  // fused grid blocks (1/CU)
#define FT 256  // fused block threads

__global__ void __launch_bounds__(FT) fused_nms(
    const float* __restrict__ boxes, const float* __restrict__ scores, int N,
    int words, int topn, int* __restrict__ order, float* __restrict__ sbox,
    unsigned long long* __restrict__ mask, unsigned int* __restrict__ pairs,
    int* __restrict__ count, unsigned int* __restrict__ wl,
    int* __restrict__ wl_count, int* __restrict__ rank_part,
    int* __restrict__ out, int cap) {
#pragma clang fp contract(off)
  extern __shared__ char smem[];
  cg::grid_group grid = cg::this_grid();
  int t = threadIdx.x;
  int b = blockIdx.x;
  int gtid = b * FT + t;
  int lane = t & 63;
  int wid = t >> 6;

  // ---------- phase 1: init counters, zero mask, tiled rank partials ------
  if (gtid == 0) {
    *count = 0;
    *wl_count = 0;
  }
  size_t mtot = (size_t)N * words;
  for (size_t idx = gtid; idx < mtot; idx += (size_t)FG * FT) mask[idx] = 0ull;

  int JT = (N + 31) / 32;  // j-tile width (<=64 for N<=2048)
  {
    float* sj = (float*)smem;
    int bi = b >> 5, bj = b & 31;
    int jbase = bj * JT;
    int jn = min(jbase + JT, N) - jbase;
    if (jn < 0) jn = 0;
    for (int k = t; k < jn; k += FT) sj[k] = scores[jbase + k];
    __syncthreads();
    int i = bi * FT + t;
    if (i < N) {
      float si = scores[i];
      int r0 = 0, r1 = 0;
      int k = 0;
#pragma unroll 4
      for (; k + 2 <= jn; k += 2) {
        float a = sj[k], c = sj[k + 1];
        int j0 = jbase + k;
        r0 += (a > si) || (a == si && j0 < i);
        r1 += (c > si) || (c == si && (j0 + 1) < i);
      }
      for (; k < jn; ++k) {
        float a = sj[k];
        r0 += (a > si) || (a == si && (jbase + k) < i);
      }
      rank_part[(size_t)bj * N + i] = r0 + r1;
    }
  }
  grid.sync();

  // ---------- phase 2: rank sum -> scatter order + prep sbox --------------
  if (gtid < N) {
    int i = gtid;
    int r = 0;
    for (int bj = 0; bj < 32; ++bj) r += rank_part[(size_t)bj * N + i];
    order[r] = i;
    float xc = boxes[i * 5 + 0], yc = boxes[i * 5 + 1];
    float w = boxes[i * 5 + 2], h = boxes[i * 5 + 3], th = boxes[i * 5 + 4];
    float ang = th * 0.017453292519943295f;
    float c = cosf(ang), sn = sinf(ang);
    float dx = w * 0.5f, dy = h * 0.5f;
    const float lx[4] = {-dx, dx, dx, -dx};
    const float ly[4] = {-dy, -dy, dy, dy};
    float* o = sbox + (size_t)r * 12;
    for (int k = 0; k < 4; ++k) {
      o[2 * k] = xc + lx[k] * c - ly[k] * sn;  // no FMA: match reference
      o[2 * k + 1] = yc + lx[k] * sn + ly[k] * c;
    }
    o[8] = xc;
    o[9] = yc;
    o[10] = 0.5f * sqrtf(w * w + h * h);
    o[11] = w * h;
  }
  grid.sync();

  // ---------- phase 3: circle+area prefilter, per-block compaction --------
  {
    float* scx = (float*)smem;
    float* scy = scx + 2048;
    float* sr = scy + 2048;
    float* sa = sr + 2048;
    unsigned int* buf = (unsigned int*)(sa + 2048);
    int* cnts = (int*)(buf + 2048);  // [0]=blk_cnt [1]=blk_base
    if (t == 0) cnts[0] = 0;
    for (int k = t; k < N; k += FT) {
      const float* o = sbox + (size_t)k * 12;
      scx[k] = o[8];
      scy[k] = o[9];
      sr[k] = o[10];
      sa[k] = o[11];
    }
    __syncthreads();
    int half = N >> 1;
    for (int rp = b; rp < half; rp += FG) {
      for (int q = 0; q < 2; ++q) {
        int i = q ? (N - 1 - rp) : rp;
        float cxi = scx[i], cyi = scy[i], ri = sr[i], ai = sa[i];
        for (int j = i + 1 + t; j < N; j += FT) {
          float ddx = scx[j] - cxi, ddy = scy[j] - cyi;
          float rs = ri + sr[j];
          float aj = sa[j];
          float mn = fminf(ai, aj), mx = fmaxf(ai, aj);
          // IoU <= min/(A+B-min): IoU>0.7 requires mn > 0.7*mx (0.699 margin)
          if (ddx * ddx + ddy * ddy <= rs * rs && mn > 0.699f * mx) {
            int idx = atomicAdd(&cnts[0], 1);
            if (idx < 2048) buf[idx] = ((unsigned)i << 16) | (unsigned)j;
          }
        }
      }
    }
    if ((N & 1) && b == 0) {  // odd-N middle row
      int i = half;
      float cxi = scx[i], cyi = scy[i], ri = sr[i], ai = sa[i];
      for (int j = i + 1 + t; j < N; j += FT) {
        float ddx = scx[j] - cxi, ddy = scy[j] - cyi;
        float rs = ri + sr[j];
        float aj = sa[j];
        float mn = fminf(ai, aj), mx = fmaxf(ai, aj);
        if (ddx * ddx + ddy * ddy <= rs * rs && mn > 0.699f * mx) {
          int idx = atomicAdd(&cnts[0], 1);
          if (idx < 2048) buf[idx] = ((unsigned)i << 16) | (unsigned)j;
        }
      }
    }
    __syncthreads();
    int n2 = cnts[0] < 2048 ? cnts[0] : 2048;
    if (t == 0) cnts[1] = atomicAdd(count, n2);
    __syncthreads();
    int base = cnts[1];
    for (int k = t; k < n2; k += FT)
      if (base + k < cap) pairs[base + k] = buf[k];
  }
  grid.sync();

  // ---------- phase 4: exact SH clip over survivors (LDS polygon) ---------
  {
    float* sc = (float*)smem;  // [bu][xy][v][FT] = 32 KB
#define SCI(bu, xy, v) sc[((((bu)*2 + (xy)) * 8) + (v)) * FT + t]
    int n = *count;
    if (n > cap) n = cap;
    for (int p = gtid; p < n; p += FG * FT) {
      unsigned int pk = pairs[p];
      int i = pk >> 16, j = pk & 0xFFFF;
      const float* A = sbox + (size_t)i * 12;
      const float* B = sbox + (size_t)j * 12;
#pragma unroll
      for (int k = 0; k < 4; ++k) {
        SCI(0, 0, k) = A[2 * k];
        SCI(0, 1, k) = A[2 * k + 1];
      }
      int cnt = 4, cur = 0;
      for (int e = 0; e < 4; ++e) {
        float ax = B[2 * e], ay = B[2 * e + 1];
        int e2 = (e + 1) & 3;
        float bx = B[2 * e2], by = B[2 * e2 + 1];
        float ex = bx - ax, ey = by - ay;
        int nxtb = cur ^ 1;
        int ncnt = 0;
        for (int k = 0; k < cnt; ++k) {
          int kn = (k + 1 < cnt) ? k + 1 : 0;
          float px = SCI(cur, 0, k), py = SCI(cur, 1, k);
          float nx = SCI(cur, 0, kn), ny = SCI(cur, 1, kn);
          float dc = ex * (py - ay) - ey * (px - ax);
          float dn = ex * (ny - ay) - ey * (nx - ax);
          bool ic = (dc >= 0.0f), inx = (dn >= 0.0f);
          if (ic) {
            if (ncnt < 8) {
              SCI(nxtb, 0, ncnt) = px;
              SCI(nxtb, 1, ncnt) = py;
            }
            ++ncnt;
          }
          if (ic != inx) {
            float denom = dc - dn;
            float tp = (fabsf(denom) > 1e-12f) ? (dc / denom) : 0.0f;
            if (ncnt < 8) {
              SCI(nxtb, 0, ncnt) = px + tp * (nx - px);
              SCI(nxtb, 1, ncnt) = py + tp * (ny - py);
            }
            ++ncnt;
          }
        }
        cnt = ncnt > 8 ? 8 : ncnt;
        cur = nxtb;
      }
      float area = 0.0f;
      for (int k = 0; k < cnt; ++k) {
        int kn = (k + 1 < cnt) ? k + 1 : 0;
        area += SCI(cur, 0, k) * SCI(cur, 1, kn) -
                SCI(cur, 0, kn) * SCI(cur, 1, k);
      }
      float inter = fmaxf(0.5f * area, 0.0f);
      float uni = A[11] + B[11] - inter;
      float iou = inter / fmaxf(uni, 1e-9f);
      if (iou > 0.7f) {
        unsigned long long old =
            atomicOr(&mask[(size_t)i * words + (j >> 6)], 1ull << (j & 63));
        if (old == 0ull) {
          int x = atomicAdd(wl_count, 1);
          if (x < WL_G_CAP) wl[x] = ((unsigned)i << 6) | (unsigned)(j >> 6);
        }
      }
    }
#undef SCI
  }
  grid.sync();

  // ---------- phase 5: greedy sweep + output (block 0 only) ---------------
  if (b != 0) return;
  {
    int* h = (int*)smem;                          // [2048]
    int* dst = h + 2048;                          // [2048]
    unsigned int* keys = (unsigned int*)(dst + 2048);  // [4096]
    unsigned long long* sup_sh = (unsigned long long*)(keys + WL_LDS_CAP);
    int* prefix = (int*)(sup_sh + 64);            // [65]
    int* wtot = prefix + 65;                      // [4]
    int n_wl = *wl_count;
    bool sparse = (words <= 32) && (N <= 2048) && (n_wl <= WL_LDS_CAP);

    if (sparse) {
      if (t < 64) sup_sh[t] = 0ull;
      for (int k = t; k < N; k += FT) h[k] = 0;
      __syncthreads();
      for (int e = t; e < n_wl; e += FT) atomicAdd(&h[wl[e] >> 6], 1);
      __syncthreads();
      // exclusive row prefix: thread owns 8 rows, two-level shfl scan
      int base_r = t * 8;
      int loc[8];
      int s = 0;
#pragma unroll
      for (int k = 0; k < 8; ++k) {
        int r = base_r + k;
        int v = (r < N) ? h[r] : 0;
        loc[k] = s;
        s += v;
      }
      int incl = s;
      for (int d = 1; d < 64; d <<= 1) {
        int v = __shfl_up(incl, d);
        if (lane >= d) incl += v;
      }
      if (lane == 63) wtot[wid] = incl;
      __syncthreads();
      if (wid == 0 && lane < 4) {
        int w = wtot[lane];
        for (int d = 1; d < 4; d <<= 1) {
          int v = __shfl_up(w, d);
          if (lane >= d) w += v;
        }
        wtot[lane] = w;  // inclusive wave totals
      }
      __syncthreads();
      int tbase = (wid ? wtot[wid - 1] : 0) + (incl - s);
#pragma unroll
      for (int k = 0; k < 8; ++k) {
        int r = base_r + k;
        if (r < N) dst[r] = tbase + loc[k];
      }
      __syncthreads();
      for (int e = t; e < n_wl; e += FT) {
        unsigned key = wl[e];
        int pos = atomicAdd(&dst[key >> 6], 1);
        keys[pos] = key;
      }
      __syncthreads();
      if (t < 64) {
        unsigned long long sup = 0ull;
        unsigned long long supg = 0ull;
        int cur_g = -1;
        int chunks = (n_wl + 63) >> 6;
        for (int c = 0; c < chunks; ++c) {
          int idx = (c << 6) + lane;
          unsigned key = (idx < n_wl) ? keys[idx] : 0u;
          unsigned long long val = 0ull;
          if (idx < n_wl) {
            int rr = key >> 6, ww = key & 63;
            val = mask[(size_t)rr * words + ww];
          }
          int lim = n_wl - (c << 6);
          if (lim > 64) lim = 64;
          for (int e = 0; e < lim; ++e) {
            unsigned k2 = __shfl(key, e);
            unsigned long long v2 = __shfl(val, e);
            int r = k2 >> 6, w = k2 & 63, g = r >> 6;
            if (g != cur_g) {
              supg = __shfl(sup, g);
              cur_g = g;
            }
            bool kept = !((supg >> (r & 63)) & 1ull);
            if (kept) {
              if (lane == w) sup |= v2;
              if (w == g) supg |= v2;
            }
          }
        }
        sup_sh[lane] = (lane < words) ? sup : 0ull;
      }
      __syncthreads();
    } else {
      // dense fallback (round-3 algorithm, 256 threads)
      if (t < 64) sup_sh[t] = 0ull;
      __syncthreads();
      int rstride = FT / words;
      int w2 = t % words;
      int rl0 = t / words;
      for (int g = 0; g < words; ++g) {
        if (wid == 0) {
          int r = g * 64 + lane;
          unsigned long long d = (r < N) ? mask[(size_t)r * words + g] : 0ull;
          unsigned long long supmask = sup_sh[g];
          for (int lp = 0; lp < 64; ++lp) {
            if (!((supmask >> lp) & 1ull)) supmask |= __shfl(d, lp);
          }
          if (lane == 0) sup_sh[g] = supmask;
        }
        __syncthreads();
        unsigned long long supg = sup_sh[g];
        if (w2 > g) {
          unsigned long long acc = 0ull;
          for (int rl = rl0; rl < 64; rl += rstride) {
            if (!((supg >> rl) & 1ull)) {
              int r = g * 64 + rl;
              if (r < N) acc |= mask[(size_t)r * words + w2];
            }
          }
          if (acc) atomicOr(&sup_sh[w2], acc);
        }
        __syncthreads();
      }
    }

    if (t == 0) {
      int acc = 0;
      for (int w = 0; w < words; ++w) {
        prefix[w] = acc;
        int hi = N - w * 64;
        unsigned long long keptw = ~sup_sh[w];
        if (hi < 64) keptw &= (1ull << hi) - 1ull;
        acc += __popcll(keptw);
      }
      prefix[words] = acc;
    }
    __syncthreads();
    int total = prefix[words];
    for (int i = t; i < N; i += FT) {
      int w = i >> 6, bb = i & 63;
      if (!((sup_sh[w] >> bb) & 1ull)) {
        int pos = prefix[w] + __popcll(~sup_sh[w] & ((1ull << bb) - 1ull));
        if (pos < topn) out[pos] = order[i];
      }
    }
    for (int k = total + t; k < topn; k += FT) out[k] = -1;
  }
}

// ======================= fallback path (N > 2048) ==========================
__device__ __forceinline__ float clip_inter_area_reg(
    const float* __restrict__ A, const float* __restrict__ B) {
#pragma clang fp contract(off)
  float Px[8], Py[8], Qx[8], Qy[8];
  for (int k = 0; k < 4; ++k) {
    Px[k] = A[2 * k];
    Py[k] = A[2 * k + 1];
  }
  int cnt = 4;
  for (int e = 0; e < 4; ++e) {
    float ax = B[2 * e], ay = B[2 * e + 1];
    int e2 = (e + 1) & 3;
    float bx = B[2 * e2], by = B[2 * e2 + 1];
    float ex = bx - ax, ey = by - ay;
    int ncnt = 0;
    for (int k = 0; k < cnt; ++k) {
      int kn = (k + 1 < cnt) ? k + 1 : 0;
      float dc = ex * (Py[k] - ay) - ey * (Px[k] - ax);
      float dn = ex * (Py[kn] - ay) - ey * (Px[kn] - ax);
      bool ic = (dc >= 0.0f), inx = (dn >= 0.0f);
      if (ic) {
        if (ncnt < 8) {
          Qx[ncnt] = Px[k];
          Qy[ncnt] = Py[k];
        }
        ++ncnt;
      }
      if (ic != inx) {
        float denom = dc - dn;
        float tp = (fabsf(denom) > 1e-12f) ? (dc / denom) : 0.0f;
        if (ncnt < 8) {
          Qx[ncnt] = Px[k] + tp * (Px[kn] - Px[k]);
          Qy[ncnt] = Py[k] + tp * (Py[kn] - Py[k]);
        }
        ++ncnt;
      }
    }
    cnt = ncnt > 8 ? 8 : ncnt;
    for (int k = 0; k < cnt; ++k) {
      Px[k] = Qx[k];
      Py[k] = Qy[k];
    }
  }
  float area = 0.0f;
  for (int k = 0; k < cnt; ++k) {
    int kn = (k + 1 < cnt) ? k + 1 : 0;
    area += Px[k] * Py[kn] - Px[kn] * Py[k];
  }
  return fmaxf(0.5f * area, 0.0f);
}

__global__ void rank_kernel_fb(const float* __restrict__ scores,
                               int* __restrict__ order, int N) {
  int i = blockIdx.x * blockDim.x + threadIdx.x;
  if (i >= N) return;
  float si = scores[i];
  int r = 0;
  for (int j = 0; j < N; ++j) {
    float sj = scores[j];
    if (sj > si || (sj == si && j < i)) ++r;
  }
  order[r] = i;
}

__global__ void prep_kernel_fb(const float* __restrict__ boxes,
                               const int* __restrict__ order,
                               float* __restrict__ sbox, int N) {
#pragma clang fp contract(off)
  int i = blockIdx.x * blockDim.x + threadIdx.x;
  if (i >= N) return;
  int bx = order[i];
  float xc = boxes[bx * 5 + 0], yc = boxes[bx * 5 + 1];
  float w = boxes[bx * 5 + 2], h = boxes[bx * 5 + 3], th = boxes[bx * 5 + 4];
  float ang = th * 0.017453292519943295f;
  float c = cosf(ang), sn = sinf(ang);
  float dx = w * 0.5f, dy = h * 0.5f;
  const float lx[4] = {-dx, dx, dx, -dx};
  const float ly[4] = {-dy, -dy, dy, dy};
  float* o = sbox + (size_t)i * 12;
  for (int k = 0; k < 4; ++k) {
    o[2 * k] = xc + lx[k] * c - ly[k] * sn;
    o[2 * k + 1] = yc + lx[k] * sn + ly[k] * c;
  }
  o[8] = xc;
  o[9] = yc;
  o[10] = 0.5f * sqrtf(w * w + h * h);
  o[11] = w * h;
}

__global__ void iou_direct_kernel(const float* __restrict__ sbox,
                                  unsigned long long* __restrict__ mask, int N,
                                  int words) {
#pragma clang fp contract(off)
  int j = blockIdx.x * blockDim.x + threadIdx.x;
  int i = blockIdx.y;
  if (j >= N || j <= i) return;
  const float* A = sbox + (size_t)i * 12;
  const float* B = sbox + (size_t)j * 12;
  float ddx = B[8] - A[8], ddy = B[9] - A[9];
  float rs = A[10] + B[10];
  if (ddx * ddx + ddy * ddy > rs * rs) return;
  float mn = fminf(A[11], B[11]), mx = fmaxf(A[11], B[11]);
  if (!(mn > 0.699f * mx)) return;
  float inter = clip_inter_area_reg(A, B);
  float uni = A[11] + B[11] - inter;
  float iou = inter / fmaxf(uni, 1e-9f);
  if (iou > 0.7f)
    atomicOr(&mask[(size_t)i * words + (j >> 6)], 1ull << (j & 63));
}

__global__ void __launch_bounds__(1024) nms_sweep_fb(
    const unsigned long long* __restrict__ mask, const int* __restrict__ order,
    int* __restrict__ out, int N, int words, int topn) {
  __shared__ unsigned long long sup[64];
  __shared__ int prefix[65];
  int t = threadIdx.x;
  int lane = t & 63;
  int wave = t >> 6;
  if (t < words) sup[t] = 0ull;
  __syncthreads();
  int rstride = 1024 / words;
  int w2 = t % words;
  int rl0 = t / words;
  for (int g = 0; g < words; ++g) {
    if (wave == 0) {
      int r = g * 64 + lane;
      unsigned long long d = (r < N) ? mask[(size_t)r * words + g] : 0ull;
      unsigned long long supmask = sup[g];
      for (int lp = 0; lp < 64; ++lp) {
        if (!((supmask >> lp) & 1ull)) supmask |= __shfl(d, lp);
      }
      if (lane == 0) sup[g] = supmask;
    }
    __syncthreads();
    unsigned long long supg = sup[g];
    if (w2 > g) {
      unsigned long long acc = 0ull;
      for (int rl = rl0; rl < 64; rl += rstride) {
        if (!((supg >> rl) & 1ull)) {
          int r = g * 64 + rl;
          if (r < N) acc |= mask[(size_t)r * words + w2];
        }
      }
      if (acc) atomicOr(&sup[w2], acc);
    }
    __syncthreads();
  }
  if (t == 0) {
    int acc = 0;
    for (int w = 0; w < words; ++w) {
      prefix[w] = acc;
      int hi = N - w * 64;
      unsigned long long keptw = ~sup[w];
      if (hi < 64) keptw &= (1ull << hi) - 1ull;
      acc += __popcll(keptw);
    }
    prefix[words] = acc;
  }
  __syncthreads();
  int total = prefix[words];
  for (int i = t; i < N; i += 1024) {
    int w = i >> 6, bb = i & 63;
    if (!((sup[w] >> bb) & 1ull)) {
      int pos = prefix[w] + __popcll(~sup[w] & ((1ull << bb) - 1ull));
      if (pos < topn) out[pos] = order[i];
    }
  }
  for (int k = total + t; k < topn; k += 1024) out[k] = -1;
}

extern "C" void kernel_launch(void* const* d_in, const int* in_sizes, int n_in,
                              void* d_out, int out_size, void* d_ws,
                              size_t ws_size, hipStream_t stream) {
  const float* boxes = (const float*)d_in[0];
  const float* scores = (const float*)d_in[1];
  int N = in_sizes[1];
  int words = (N + 63) / 64;

  char* ws = (char*)d_ws;
  size_t off = 0;
  unsigned long long* mask = (unsigned long long*)(ws + off);
  off += (size_t)N * words * sizeof(unsigned long long);
  float* sbox = (float*)(ws + off);
  off += (size_t)N * 12 * sizeof(float);
  int* order = (int*)(ws + off);
  off += (size_t)N * sizeof(int);
  int* count = (int*)(ws + off);
  int* wl_count = count + 1;
  off += 16;
  unsigned int* wl = (unsigned int*)(ws + off);
  off += (size_t)WL_G_CAP * sizeof(unsigned int);
  int* rank_part = (int*)(ws + off);
  off += (size_t)32 * N * sizeof(int);
  unsigned int* pairs = (unsigned int*)(ws + off);
  size_t maxpairs = (size_t)N * (N - 1) / 2;
  bool fused_ok = (N <= 2048) && (off + maxpairs * 4 <= ws_size);
  int cap = (int)maxpairs;
  int topn = out_size;
  int* out = (int*)d_out;

  if (fused_ok) {
    // smem arena: max(phase3 = 5*2048*4+16, phase4 = 32K, phase5 ~ 33.6K)
    unsigned int smem = 4 * 2048 * 4 + 2048 * 4 + 64;
    void* args[] = {(void*)&boxes, (void*)&scores,   (void*)&N,
                    (void*)&words, (void*)&topn,     (void*)&order,
                    (void*)&sbox,  (void*)&mask,     (void*)&pairs,
                    (void*)&count, (void*)&wl,       (void*)&wl_count,
                    (void*)&rank_part, (void*)&out,  (void*)&cap};
    hipLaunchCooperativeKernel((const void*)fused_nms, dim3(FG), dim3(FT),
                               args, smem, stream);
  } else {
    int nb = (N + 255) / 256;
    hipMemsetAsync(mask, 0, (size_t)N * words * 8, stream);
    rank_kernel_fb<<<nb, 256, 0, stream>>>(scores, order, N);
    prep_kernel_fb<<<nb, 256, 0, stream>>>(boxes, order, sbox, N);
    dim3 grid(nb, N);
    iou_direct_kernel<<<grid, 256, 0, stream>>>(sbox, mask, N, words);
    nms_sweep_fb<<<1, 1024, 0, stream>>>(mask, order, out, N, words, topn);
  }
}

// Round 9
// 94.817 us; speedup vs baseline: 2.0532x; 2.0532x over previous
//
#include <hip/hip_runtime.h>

// Rotated NMS, N boxes [xc,yc,w,h,theta_deg], scores. Output: first 1000 kept
// original indices in score-sorted order, -1 padded. IoU math replicates the
// reference's float32 op order (contract off) — rounds 1-8: absmax 0.
//
// Round 9: back to multi-dispatch (round-8 lesson: grid.sync costs ~30 us on
// 8 non-coherent XCD L2s; fusion regressed 2x). Pipeline shortened to THREE
// kernels by eliminating the sbox intermediate: consumers recompute geometry
// from boxes[] directly (bit-identical expressions).

#define WL_LDS_CAP 4096
#define WL_G_CAP 65536

// ---------------- K1: rank + order (+ mask zero, counter init) ------------
// 8 i per block x 32 j-lanes per i; lane l sums j == l (mod 32) -> LDS
// conflict-free (bank = j%32 = lane). Butterfly reduce within 32-lane group.
__global__ void __launch_bounds__(256) rank_order(
    const float* __restrict__ scores, int* __restrict__ order,
    unsigned long long* __restrict__ mask, int words,
    int* __restrict__ wl_count, int N) {
  __shared__ float s[2048];
  int t = threadIdx.x;
  int gtid = blockIdx.x * 256 + t;
  if (gtid == 0) *wl_count = 0;
  size_t mtot = (size_t)N * words;
  for (size_t k = gtid; k < mtot; k += (size_t)gridDim.x * 256) mask[k] = 0ull;
  for (int k = t; k < N; k += 256) s[k] = scores[k];
  __syncthreads();
  int il = t >> 5, jc = t & 31;
  int i = blockIdx.x * 8 + il;
  int r = 0;
  if (i < N) {
    float si = s[i];
#pragma unroll 8
    for (int j = jc; j < N; j += 32) {
      float a = s[j];
      r += (a > si) || (a == si && j < i);
    }
  }
  r += __shfl_xor(r, 1);
  r += __shfl_xor(r, 2);
  r += __shfl_xor(r, 4);
  r += __shfl_xor(r, 8);
  r += __shfl_xor(r, 16);
  if (i < N && jc == 0) order[r] = i;
}

// Corners from box params — identical fp expressions to rounds 1-8.
__device__ __forceinline__ void make_corners(const float* __restrict__ bp,
                                             float* __restrict__ cr) {
#pragma clang fp contract(off)
  float xc = bp[0], yc = bp[1], w = bp[2], h = bp[3], th = bp[4];
  float ang = th * 0.017453292519943295f;
  float c = cosf(ang), sn = sinf(ang);
  float dx = w * 0.5f, dy = h * 0.5f;
  const float lx[4] = {-dx, dx, dx, -dx};
  const float ly[4] = {-dy, -dy, dy, dy};
#pragma unroll
  for (int k = 0; k < 4; ++k) {
    cr[2 * k] = xc + lx[k] * c - ly[k] * sn;  // no FMA: match reference
    cr[2 * k + 1] = yc + lx[k] * sn + ly[k] * c;
  }
}

// Register-array SH clip (overflow path only; static corner indices, dynamic
// polygon may spill to scratch — rare).
__device__ float clip_inter_area_reg(const float* __restrict__ A,
                                     const float* __restrict__ B) {
#pragma clang fp contract(off)
  float Px[8], Py[8], Qx[8], Qy[8];
  for (int k = 0; k < 4; ++k) {
    Px[k] = A[2 * k];
    Py[k] = A[2 * k + 1];
  }
  int cnt = 4;
  for (int e = 0; e < 4; ++e) {
    float ax = B[2 * e], ay = B[2 * e + 1];
    int e2 = (e + 1) & 3;
    float bx = B[2 * e2], by = B[2 * e2 + 1];
    float ex = bx - ax, ey = by - ay;
    int ncnt = 0;
    for (int k = 0; k < cnt; ++k) {
      int kn = (k + 1 < cnt) ? k + 1 : 0;
      float dc = ex * (Py[k] - ay) - ey * (Px[k] - ax);
      float dn = ex * (Py[kn] - ay) - ey * (Px[kn] - ax);
      bool ic = (dc >= 0.0f), inx = (dn >= 0.0f);
      if (ic) {
        if (ncnt < 8) {
          Qx[ncnt] = Px[k];
          Qy[ncnt] = Py[k];
        }
        ++ncnt;
      }
      if (ic != inx) {
        float denom = dc - dn;
        float tp = (fabsf(denom) > 1e-12f) ? (dc / denom) : 0.0f;
        if (ncnt < 8) {
          Qx[ncnt] = Px[k] + tp * (Px[kn] - Px[k]);
          Qy[ncnt] = Py[k] + tp * (Py[kn] - Py[k]);
        }
        ++ncnt;
      }
    }
    cnt = ncnt > 8 ? 8 : ncnt;
    for (int k = 0; k < cnt; ++k) {
      Px[k] = Qx[k];
      Py[k] = Qy[k];
    }
  }
  float area = 0.0f;
  for (int k = 0; k < cnt; ++k) {
    int kn = (k + 1 < cnt) ? k + 1 : 0;
    area += Px[k] * Py[kn] - Px[kn] * Py[k];
  }
  return fmaxf(0.5f * area, 0.0f);
}

__device__ __forceinline__ void emit_pair(float inter, float ai, float aj,
                                          int i, int j,
                                          unsigned long long* __restrict__ mask,
                                          int words,
                                          unsigned int* __restrict__ wl,
                                          int* __restrict__ wl_count) {
#pragma clang fp contract(off)
  float uni = ai + aj - inter;
  float iou = inter / fmaxf(uni, 1e-9f);
  if (iou > 0.7f) {
    unsigned long long old =
        atomicOr(&mask[(size_t)i * words + (j >> 6)], 1ull << (j & 63));
    if (old == 0ull) {
      int x = atomicAdd(wl_count, 1);
      if (x < WL_G_CAP) wl[x] = ((unsigned)i << 6) | (unsigned)(j >> 6);
    }
  }
}

// ---------------- K2: circle+area prefilter + exact clip (sorted space) ---
#define CF_T 256
__global__ void __launch_bounds__(CF_T) circle_clip(
    const float* __restrict__ boxes, const int* __restrict__ order,
    unsigned long long* __restrict__ mask, int words,
    unsigned int* __restrict__ wl, int* __restrict__ wl_count, int N) {
#pragma clang fp contract(off)
  __shared__ float cx[2048], cy[2048], rr[2048], aa[2048];
  __shared__ int ordl[2048];
  __shared__ unsigned int buf[2048];
  __shared__ int bcnt;
  __shared__ float poly[2][2][8][CF_T];  // 32 KB, lane-major: conflict-free
  int t = threadIdx.x;
  if (t == 0) bcnt = 0;
  for (int k = t; k < N; k += CF_T) {  // stage in SORTED space
    int o = order[k];
    ordl[k] = o;
    const float* bp = boxes + 5 * o;
    float w = bp[2], h = bp[3];
    cx[k] = bp[0];
    cy[k] = bp[1];
    rr[k] = 0.5f * sqrtf(w * w + h * h);
    aa[k] = w * h;
  }
  __syncthreads();
  int half = N >> 1;
  for (int rp = blockIdx.x; rp < half; rp += gridDim.x) {
    for (int q = 0; q < 2; ++q) {
      int i = q ? (N - 1 - rp) : rp;  // balanced row pair
      float cxi = cx[i], cyi = cy[i], ri = rr[i], ai = aa[i];
      for (int j = i + 1 + t; j < N; j += CF_T) {
        float ddx = cx[j] - cxi, ddy = cy[j] - cyi;
        float rs = ri + rr[j];
        float aj = aa[j];
        float mn = fminf(ai, aj), mx = fmaxf(ai, aj);
        // IoU <= min/(A+B-min): IoU>0.7 requires mn > 0.7*mx (0.699 margin)
        if (ddx * ddx + ddy * ddy <= rs * rs && mn > 0.699f * mx) {
          int idx = atomicAdd(&bcnt, 1);
          if (idx < 2048) {
            buf[idx] = ((unsigned)i << 16) | (unsigned)j;
          } else {  // overflow: inline register clip (rare, correct)
            float CA[8], CB[8];
            make_corners(boxes + 5 * ordl[i], CA);
            make_corners(boxes + 5 * ordl[j], CB);
            float inter = clip_inter_area_reg(CA, CB);
            emit_pair(inter, ai, aj, i, j, mask, words, wl, wl_count);
          }
        }
      }
    }
  }
  if ((N & 1) && blockIdx.x == 0) {  // odd-N middle row
    int i = half;
    float cxi = cx[i], cyi = cy[i], ri = rr[i], ai = aa[i];
    for (int j = i + 1 + t; j < N; j += CF_T) {
      float ddx = cx[j] - cxi, ddy = cy[j] - cyi;
      float rs = ri + rr[j];
      float aj = aa[j];
      float mn = fminf(ai, aj), mx = fmaxf(ai, aj);
      if (ddx * ddx + ddy * ddy <= rs * rs && mn > 0.699f * mx) {
        int idx = atomicAdd(&bcnt, 1);
        if (idx < 2048) {
          buf[idx] = ((unsigned)i << 16) | (unsigned)j;
        } else {
          float CA[8], CB[8];
          make_corners(boxes + 5 * ordl[i], CA);
          make_corners(boxes + 5 * ordl[j], CB);
          float inter = clip_inter_area_reg(CA, CB);
          emit_pair(inter, ai, aj, i, j, mask, words, wl, wl_count);
        }
      }
    }
  }
  __syncthreads();
  int n = bcnt < 2048 ? bcnt : 2048;
  // exact SH clip of buffered survivors, polygon in LDS
  for (int p = t; p < n; p += CF_T) {
    unsigned int pk = buf[p];
    int i = pk >> 16, j = pk & 0xFFFF;
    float CA[8], CB[8];
    make_corners(boxes + 5 * ordl[i], CA);  // subject = suppressor row i
    make_corners(boxes + 5 * ordl[j], CB);  // clipper = candidate j
#pragma unroll
    for (int k = 0; k < 4; ++k) {
      poly[0][0][k][t] = CA[2 * k];
      poly[0][1][k][t] = CA[2 * k + 1];
    }
    int cnt = 4, cur = 0;
    for (int e = 0; e < 4; ++e) {
      float ax = CB[2 * e], ay = CB[2 * e + 1];
      int e2 = (e + 1) & 3;
      float bx = CB[2 * e2], by = CB[2 * e2 + 1];
      float ex = bx - ax, ey = by - ay;
      int nxtb = cur ^ 1;
      int ncnt = 0;
      for (int k = 0; k < cnt; ++k) {
        int kn = (k + 1 < cnt) ? k + 1 : 0;
        float px = poly[cur][0][k][t], py = poly[cur][1][k][t];
        float nx = poly[cur][0][kn][t], ny = poly[cur][1][kn][t];
        float dc = ex * (py - ay) - ey * (px - ax);
        float dn = ex * (ny - ay) - ey * (nx - ax);
        bool ic = (dc >= 0.0f), inx = (dn >= 0.0f);
        if (ic) {
          if (ncnt < 8) {
            poly[nxtb][0][ncnt][t] = px;
            poly[nxtb][1][ncnt][t] = py;
          }
          ++ncnt;
        }
        if (ic != inx) {
          float denom = dc - dn;
          float tp = (fabsf(denom) > 1e-12f) ? (dc / denom) : 0.0f;
          if (ncnt < 8) {
            poly[nxtb][0][ncnt][t] = px + tp * (nx - px);
            poly[nxtb][1][ncnt][t] = py + tp * (ny - py);
          }
          ++ncnt;
        }
      }
      cnt = ncnt > 8 ? 8 : ncnt;
      cur = nxtb;
    }
    float area = 0.0f;
    for (int k = 0; k < cnt; ++k) {
      int kn = (k + 1 < cnt) ? k + 1 : 0;
      area += poly[cur][0][k][t] * poly[cur][1][kn][t] -
              poly[cur][0][kn][t] * poly[cur][1][k][t];
    }
    float inter = fmaxf(0.5f * area, 0.0f);
    emit_pair(inter, aa[i], aa[j], i, j, mask, words, wl, wl_count);
  }
}

// ---------------- K3: greedy sweep (round-7 version, verified) ------------
__global__ void __launch_bounds__(1024) nms_sweep(
    const unsigned long long* __restrict__ mask, const int* __restrict__ order,
    const unsigned int* __restrict__ wl, const int* __restrict__ wl_count,
    int* __restrict__ out, int N, int words, int topn) {
  __shared__ unsigned long long sup_sh[64];
  __shared__ int prefix[65];
  __shared__ int h[2048], dst[2048];
  __shared__ int wtot[16];
  __shared__ unsigned int keys[WL_LDS_CAP];
  int t = threadIdx.x;
  int lane = t & 63;
  int wid = t >> 6;
  int n_wl = *wl_count;
  bool sparse = (words <= 32) && (N <= 2048) && (n_wl <= WL_LDS_CAP);

  if (sparse) {
    if (t < 64) sup_sh[t] = 0ull;
    for (int k = t; k < N; k += 1024) h[k] = 0;
    __syncthreads();
    for (int e = t; e < n_wl; e += 1024) atomicAdd(&h[wl[e] >> 6], 1);
    __syncthreads();
    int a = (2 * t < N) ? h[2 * t] : 0;
    int b = (2 * t + 1 < N) ? h[2 * t + 1] : 0;
    int s = a + b;
    for (int d = 1; d < 64; d <<= 1) {
      int v = __shfl_up(s, d);
      if (lane >= d) s += v;
    }
    if (lane == 63) wtot[wid] = s;
    __syncthreads();
    if (wid == 0) {
      int w = (lane < 16) ? wtot[lane] : 0;
      for (int d = 1; d < 16; d <<= 1) {
        int v = __shfl_up(w, d);
        if (lane >= d) w += v;
      }
      if (lane < 16) wtot[lane] = w;
    }
    __syncthreads();
    int base = (wid ? wtot[wid - 1] : 0) + (s - (a + b));
    if (2 * t < N) dst[2 * t] = base;
    if (2 * t + 1 < N) dst[2 * t + 1] = base + a;
    __syncthreads();
    for (int e = t; e < n_wl; e += 1024) {
      unsigned key = wl[e];
      int pos = atomicAdd(&dst[key >> 6], 1);
      keys[pos] = key;
    }
    __syncthreads();
    if (t < 64) {
      unsigned long long sup = 0ull;
      unsigned long long supg = 0ull;
      int cur_g = -1;
      int chunks = (n_wl + 63) >> 6;
      for (int c = 0; c < chunks; ++c) {
        int idx = (c << 6) + lane;
        unsigned key = (idx < n_wl) ? keys[idx] : 0u;
        unsigned long long val = 0ull;
        if (idx < n_wl) {
          int rr2 = key >> 6, ww = key & 63;
          val = mask[(size_t)rr2 * words + ww];
        }
        int lim = n_wl - (c << 6);
        if (lim > 64) lim = 64;
        for (int e = 0; e < lim; ++e) {
          unsigned k2 = __shfl(key, e);
          unsigned long long v2 = __shfl(val, e);
          int r = k2 >> 6, w = k2 & 63, g = r >> 6;
          if (g != cur_g) {
            supg = __shfl(sup, g);
            cur_g = g;
          }
          bool kept = !((supg >> (r & 63)) & 1ull);
          if (kept) {
            if (lane == w) sup |= v2;
            if (w == g) supg |= v2;
          }
        }
      }
      sup_sh[lane] = (lane < words) ? sup : 0ull;
    }
    __syncthreads();
  } else {
    if (t < 64) sup_sh[t] = 0ull;
    __syncthreads();
    int rstride = 1024 / words;
    int w2 = t % words;
    int rl0 = t / words;
    for (int g = 0; g < words; ++g) {
      if (wid == 0) {
        int r = g * 64 + lane;
        unsigned long long d = (r < N) ? mask[(size_t)r * words + g] : 0ull;
        unsigned long long supmask = sup_sh[g];
        for (int lp = 0; lp < 64; ++lp) {
          if (!((supmask >> lp) & 1ull)) supmask |= __shfl(d, lp);
        }
        if (lane == 0) sup_sh[g] = supmask;
      }
      __syncthreads();
      unsigned long long supg = sup_sh[g];
      if (w2 > g) {
        unsigned long long acc = 0ull;
        for (int rl = rl0; rl < 64; rl += rstride) {
          if (!((supg >> rl) & 1ull)) {
            int r = g * 64 + rl;
            if (r < N) acc |= mask[(size_t)r * words + w2];
          }
        }
        if (acc) atomicOr(&sup_sh[w2], acc);
      }
      __syncthreads();
    }
  }

  if (t == 0) {
    int acc = 0;
    for (int w = 0; w < words; ++w) {
      prefix[w] = acc;
      int hi = N - w * 64;
      unsigned long long keptw = ~sup_sh[w];
      if (hi < 64) keptw &= (1ull << hi) - 1ull;
      acc += __popcll(keptw);
    }
    prefix[words] = acc;
  }
  __syncthreads();
  int total = prefix[words];
  for (int i = t; i < N; i += 1024) {
    int w = i >> 6, bb = i & 63;
    if (!((sup_sh[w] >> bb) & 1ull)) {
      int pos = prefix[w] + __popcll(~sup_sh[w] & ((1ull << bb) - 1ull));
      if (pos < topn) out[pos] = order[i];
    }
  }
  for (int k = total + t; k < topn; k += 1024) out[k] = -1;
}

// =================== fallback path (N > 2048) =============================
__global__ void rank_kernel_fb(const float* __restrict__ scores,
                               int* __restrict__ order, int N) {
  int i = blockIdx.x * blockDim.x + threadIdx.x;
  if (i >= N) return;
  float si = scores[i];
  int r = 0;
  for (int j = 0; j < N; ++j) {
    float sj = scores[j];
    if (sj > si || (sj == si && j < i)) ++r;
  }
  order[r] = i;
}

__global__ void prep_kernel_fb(const float* __restrict__ boxes,
                               const int* __restrict__ order,
                               float* __restrict__ sbox, int N) {
#pragma clang fp contract(off)
  int i = blockIdx.x * blockDim.x + threadIdx.x;
  if (i >= N) return;
  int bx = order[i];
  const float* bp = boxes + 5 * bx;
  float w = bp[2], h = bp[3];
  float* o = sbox + (size_t)i * 12;
  make_corners(bp, o);
  o[8] = bp[0];
  o[9] = bp[1];
  o[10] = 0.5f * sqrtf(w * w + h * h);
  o[11] = w * h;
}

__global__ void iou_direct_kernel(const float* __restrict__ sbox,
                                  unsigned long long* __restrict__ mask, int N,
                                  int words) {
#pragma clang fp contract(off)
  int j = blockIdx.x * blockDim.x + threadIdx.x;
  int i = blockIdx.y;
  if (j >= N || j <= i) return;
  const float* A = sbox + (size_t)i * 12;
  const float* B = sbox + (size_t)j * 12;
  float ddx = B[8] - A[8], ddy = B[9] - A[9];
  float rs = A[10] + B[10];
  if (ddx * ddx + ddy * ddy > rs * rs) return;
  float mn = fminf(A[11], B[11]), mx = fmaxf(A[11], B[11]);
  if (!(mn > 0.699f * mx)) return;
  float inter = clip_inter_area_reg(A, B);
  float uni = A[11] + B[11] - inter;
  float iou = inter / fmaxf(uni, 1e-9f);
  if (iou > 0.7f)
    atomicOr(&mask[(size_t)i * words + (j >> 6)], 1ull << (j & 63));
}

__global__ void __launch_bounds__(1024) nms_sweep_fb(
    const unsigned long long* __restrict__ mask, const int* __restrict__ order,
    int* __restrict__ out, int N, int words, int topn) {
  __shared__ unsigned long long sup[64];
  __shared__ int prefix[65];
  int t = threadIdx.x;
  int lane = t & 63;
  int wave = t >> 6;
  if (t < words) sup[t] = 0ull;
  __syncthreads();
  int rstride = 1024 / words;
  int w2 = t % words;
  int rl0 = t / words;
  for (int g = 0; g < words; ++g) {
    if (wave == 0) {
      int r = g * 64 + lane;
      unsigned long long d = (r < N) ? mask[(size_t)r * words + g] : 0ull;
      unsigned long long supmask = sup[g];
      for (int lp = 0; lp < 64; ++lp) {
        if (!((supmask >> lp) & 1ull)) supmask |= __shfl(d, lp);
      }
      if (lane == 0) sup[g] = supmask;
    }
    __syncthreads();
    unsigned long long supg = sup[g];
    if (w2 > g) {
      unsigned long long acc = 0ull;
      for (int rl = rl0; rl < 64; rl += rstride) {
        if (!((supg >> rl) & 1ull)) {
          int r = g * 64 + rl;
          if (r < N) acc |= mask[(size_t)r * words + w2];
        }
      }
      if (acc) atomicOr(&sup[w2], acc);
    }
    __syncthreads();
  }
  if (t == 0) {
    int acc = 0;
    for (int w = 0; w < words; ++w) {
      prefix[w] = acc;
      int hi = N - w * 64;
      unsigned long long keptw = ~sup[w];
      if (hi < 64) keptw &= (1ull << hi) - 1ull;
      acc += __popcll(keptw);
    }
    prefix[words] = acc;
  }
  __syncthreads();
  int total = prefix[words];
  for (int i = t; i < N; i += 1024) {
    int w = i >> 6, bb = i & 63;
    if (!((sup[w] >> bb) & 1ull)) {
      int pos = prefix[w] + __popcll(~sup[w] & ((1ull << bb) - 1ull));
      if (pos < topn) out[pos] = order[i];
    }
  }
  for (int k = total + t; k < topn; k += 1024) out[k] = -1;
}

extern "C" void kernel_launch(void* const* d_in, const int* in_sizes, int n_in,
                              void* d_out, int out_size, void* d_ws,
                              size_t ws_size, hipStream_t stream) {
  const float* boxes = (const float*)d_in[0];
  const float* scores = (const float*)d_in[1];
  int N = in_sizes[1];
  int words = (N + 63) / 64;

  char* ws = (char*)d_ws;
  size_t off = 0;
  unsigned long long* mask = (unsigned long long*)(ws + off);
  off += (size_t)N * words * sizeof(unsigned long long);
  int* order = (int*)(ws + off);
  off += (size_t)N * sizeof(int);
  int* wl_count = (int*)(ws + off);
  off += 16;
  unsigned int* wl = (unsigned int*)(ws + off);
  off += (size_t)WL_G_CAP * sizeof(unsigned int);
  float* sbox = (float*)(ws + off);  // fallback only
  off += (size_t)N * 12 * sizeof(float);

  int topn = out_size;
  int* out = (int*)d_out;

  if (N <= 2048) {
    int rb = (N + 7) / 8;
    rank_order<<<rb, 256, 0, stream>>>(scores, order, mask, words, wl_count,
                                       N);
    circle_clip<<<256, CF_T, 0, stream>>>(boxes, order, mask, words, wl,
                                          wl_count, N);
    nms_sweep<<<1, 1024, 0, stream>>>(mask, order, wl, wl_count, out, N, words,
                                      topn);
  } else {
    int nb = (N + 255) / 256;
    hipMemsetAsync(mask, 0, (size_t)N * words * 8, stream);
    rank_kernel_fb<<<nb, 256, 0, stream>>>(scores, order, N);
    prep_kernel_fb<<<nb, 256, 0, stream>>>(boxes, order, sbox, N);
    dim3 grid(nb, N);
    iou_direct_kernel<<<grid, 256, 0, stream>>>(sbox, mask, N, words);
    nms_sweep_fb<<<1, 1024, 0, stream>>>(mask, order, out, N, words, topn);
  }
}

// Round 10
// 89.397 us; speedup vs baseline: 2.1777x; 1.0606x over previous
//
#include <hip/hip_runtime.h>

// Rotated NMS, N boxes [xc,yc,w,h,theta_deg], scores. Output: first 1000 kept
// original indices in score-sorted order, -1 padded. IoU math replicates the
// reference's float32 op order (contract off) — rounds 1-9: absmax 0.
//
// Round 10: circle_clip was 44.8 us at 1 block/CU, 96% idle (r9 profile).
// (1) rank_order now emits geo[rank]={cx,cy,r,area} so circle_clip stages
// coalesced float4 (no order->boxes gather chain); (2) overflow clip uses
// the LDS poly slot (kills scratch, VGPR 132->~64); (3) LDS 112.5->80 KB,
// 512 blocks -> 2 blocks/CU; (4) sweep prefetches mask words to LDS in
// parallel before the serial chain.

#define WL_LDS_CAP 4096
#define WL_G_CAP 65536
#define CF_T 256

// ---------------- K1: rank + order + geo (+ mask zero, counter init) ------
__global__ void __launch_bounds__(256) rank_order(
    const float* __restrict__ boxes, const float* __restrict__ scores,
    int* __restrict__ order, float4* __restrict__ geo,
    unsigned long long* __restrict__ mask, int words,
    int* __restrict__ wl_count, int N) {
#pragma clang fp contract(off)
  __shared__ float s[2048];
  int t = threadIdx.x;
  int gtid = blockIdx.x * 256 + t;
  if (gtid == 0) *wl_count = 0;
  size_t mtot = (size_t)N * words;
  for (size_t k = gtid; k < mtot; k += (size_t)gridDim.x * 256) mask[k] = 0ull;
  for (int k = t; k < N; k += 256) s[k] = scores[k];
  __syncthreads();
  int il = t >> 5, jc = t & 31;
  int i = blockIdx.x * 8 + il;
  int r = 0;
  if (i < N) {
    float si = s[i];
#pragma unroll 8
    for (int j = jc; j < N; j += 32) {
      float a = s[j];
      r += (a > si) || (a == si && j < i);
    }
  }
  r += __shfl_xor(r, 1);
  r += __shfl_xor(r, 2);
  r += __shfl_xor(r, 4);
  r += __shfl_xor(r, 8);
  r += __shfl_xor(r, 16);
  if (i < N && jc == 0) {
    order[r] = i;
    const float* bp = boxes + 5 * i;
    float w = bp[2], h = bp[3];
    float4 g;
    g.x = bp[0];
    g.y = bp[1];
    g.z = 0.5f * sqrtf(w * w + h * h);  // bounding-circle radius
    g.w = w * h;                        // area (exact, matches reference)
    geo[r] = g;
  }
}

// Corners from box params — identical fp expressions to rounds 1-9.
__device__ __forceinline__ void make_corners(const float* __restrict__ bp,
                                             float* __restrict__ cr) {
#pragma clang fp contract(off)
  float xc = bp[0], yc = bp[1], w = bp[2], h = bp[3], th = bp[4];
  float ang = th * 0.017453292519943295f;
  float c = cosf(ang), sn = sinf(ang);
  float dx = w * 0.5f, dy = h * 0.5f;
  const float lx[4] = {-dx, dx, dx, -dx};
  const float ly[4] = {-dy, -dy, dy, dy};
#pragma unroll
  for (int k = 0; k < 4; ++k) {
    cr[2 * k] = xc + lx[k] * c - ly[k] * sn;  // no FMA: match reference
    cr[2 * k + 1] = yc + lx[k] * sn + ly[k] * c;
  }
}

// Exact SH clip, polygon in per-thread LDS slot (no scratch, no conflicts:
// lane-major stride-1).
#define PIDX(bu, xy, v) ((((bu) * 2 + (xy)) * 8 + (v)) * CF_T + (t))
__device__ float clip_poly_lds(float* __restrict__ poly, int t,
                               const float* __restrict__ CA,
                               const float* __restrict__ CB) {
#pragma clang fp contract(off)
#pragma unroll
  for (int k = 0; k < 4; ++k) {
    poly[PIDX(0, 0, k)] = CA[2 * k];
    poly[PIDX(0, 1, k)] = CA[2 * k + 1];
  }
  int cnt = 4, cur = 0;
  for (int e = 0; e < 4; ++e) {
    float ax = CB[2 * e], ay = CB[2 * e + 1];
    int e2 = (e + 1) & 3;
    float bx = CB[2 * e2], by = CB[2 * e2 + 1];
    float ex = bx - ax, ey = by - ay;
    int nxtb = cur ^ 1;
    int ncnt = 0;
    for (int k = 0; k < cnt; ++k) {
      int kn = (k + 1 < cnt) ? k + 1 : 0;
      float px = poly[PIDX(cur, 0, k)], py = poly[PIDX(cur, 1, k)];
      float nx = poly[PIDX(cur, 0, kn)], ny = poly[PIDX(cur, 1, kn)];
      float dc = ex * (py - ay) - ey * (px - ax);
      float dn = ex * (ny - ay) - ey * (nx - ax);
      bool ic = (dc >= 0.0f), inx = (dn >= 0.0f);
      if (ic) {
        if (ncnt < 8) {
          poly[PIDX(nxtb, 0, ncnt)] = px;
          poly[PIDX(nxtb, 1, ncnt)] = py;
        }
        ++ncnt;
      }
      if (ic != inx) {
        float denom = dc - dn;
        float tp = (fabsf(denom) > 1e-12f) ? (dc / denom) : 0.0f;
        if (ncnt < 8) {
          poly[PIDX(nxtb, 0, ncnt)] = px + tp * (nx - px);
          poly[PIDX(nxtb, 1, ncnt)] = py + tp * (ny - py);
        }
        ++ncnt;
      }
    }
    cnt = ncnt > 8 ? 8 : ncnt;
    cur = nxtb;
  }
  float area = 0.0f;
  for (int k = 0; k < cnt; ++k) {
    int kn = (k + 1 < cnt) ? k + 1 : 0;
    area += poly[PIDX(cur, 0, k)] * poly[PIDX(cur, 1, kn)] -
            poly[PIDX(cur, 0, kn)] * poly[PIDX(cur, 1, k)];
  }
  return fmaxf(0.5f * area, 0.0f);
}

__device__ __forceinline__ void emit_pair(float inter, float ai, float aj,
                                          int i, int j,
                                          unsigned long long* __restrict__ mask,
                                          int words,
                                          unsigned int* __restrict__ wl,
                                          int* __restrict__ wl_count) {
#pragma clang fp contract(off)
  float uni = ai + aj - inter;
  float iou = inter / fmaxf(uni, 1e-9f);
  if (iou > 0.7f) {
    unsigned long long old =
        atomicOr(&mask[(size_t)i * words + (j >> 6)], 1ull << (j & 63));
    if (old == 0ull) {
      int x = atomicAdd(wl_count, 1);
      if (x < WL_G_CAP) wl[x] = ((unsigned)i << 6) | (unsigned)(j >> 6);
    }
  }
}

// ---------------- K2: circle+area prefilter + exact clip (sorted space) ---
// LDS: cx/cy/rr/aa 32K + ordl 8K + buf 8K + poly 32K = 80 KB -> 2 blocks/CU.
__global__ void __launch_bounds__(CF_T) circle_clip(
    const float* __restrict__ boxes, const int* __restrict__ order,
    const float4* __restrict__ geo, unsigned long long* __restrict__ mask,
    int words, unsigned int* __restrict__ wl, int* __restrict__ wl_count,
    int N) {
#pragma clang fp contract(off)
  __shared__ float cx[2048], cy[2048], rr[2048], aa[2048];
  __shared__ int ordl[2048];
  __shared__ unsigned int buf[2048];
  __shared__ int bcnt;
  __shared__ float poly[2 * 2 * 8 * CF_T];  // 32 KB
  int t = threadIdx.x;
  if (t == 0) bcnt = 0;
  for (int k = t; k < N; k += CF_T) {  // coalesced staging (r10)
    float4 g = geo[k];
    cx[k] = g.x;
    cy[k] = g.y;
    rr[k] = g.z;
    aa[k] = g.w;
    ordl[k] = order[k];
  }
  __syncthreads();
  int half = N >> 1;
  for (int rp = blockIdx.x; rp < half; rp += gridDim.x) {
    for (int q = 0; q < 2; ++q) {
      int i = q ? (N - 1 - rp) : rp;  // balanced row pair
      float cxi = cx[i], cyi = cy[i], ri = rr[i], ai = aa[i];
      for (int j = i + 1 + t; j < N; j += CF_T) {
        float ddx = cx[j] - cxi, ddy = cy[j] - cyi;
        float rs = ri + rr[j];
        float aj = aa[j];
        float mn = fminf(ai, aj), mx = fmaxf(ai, aj);
        // IoU <= min/(A+B-min): IoU>0.7 requires mn > 0.7*mx (0.699 margin)
        if (ddx * ddx + ddy * ddy <= rs * rs && mn > 0.699f * mx) {
          int idx = atomicAdd(&bcnt, 1);
          if (idx < 2048) {
            buf[idx] = ((unsigned)i << 16) | (unsigned)j;
          } else {  // overflow (adversarial only): clip inline via LDS slot
            float CA[8], CB[8];
            make_corners(boxes + 5 * ordl[i], CA);
            make_corners(boxes + 5 * ordl[j], CB);
            float inter = clip_poly_lds(poly, t, CA, CB);
            emit_pair(inter, ai, aj, i, j, mask, words, wl, wl_count);
          }
        }
      }
    }
  }
  if ((N & 1) && blockIdx.x == 0) {  // odd-N middle row
    int i = half;
    float cxi = cx[i], cyi = cy[i], ri = rr[i], ai = aa[i];
    for (int j = i + 1 + t; j < N; j += CF_T) {
      float ddx = cx[j] - cxi, ddy = cy[j] - cyi;
      float rs = ri + rr[j];
      float aj = aa[j];
      float mn = fminf(ai, aj), mx = fmaxf(ai, aj);
      if (ddx * ddx + ddy * ddy <= rs * rs && mn > 0.699f * mx) {
        int idx = atomicAdd(&bcnt, 1);
        if (idx < 2048) {
          buf[idx] = ((unsigned)i << 16) | (unsigned)j;
        } else {
          float CA[8], CB[8];
          make_corners(boxes + 5 * ordl[i], CA);
          make_corners(boxes + 5 * ordl[j], CB);
          float inter = clip_poly_lds(poly, t, CA, CB);
          emit_pair(inter, ai, aj, i, j, mask, words, wl, wl_count);
        }
      }
    }
  }
  __syncthreads();
  int n = bcnt < 2048 ? bcnt : 2048;
  for (int p = t; p < n; p += CF_T) {
    unsigned int pk = buf[p];
    int i = pk >> 16, j = pk & 0xFFFF;
    float CA[8], CB[8];
    make_corners(boxes + 5 * ordl[i], CA);  // subject = suppressor row i
    make_corners(boxes + 5 * ordl[j], CB);  // clipper = candidate j
    float inter = clip_poly_lds(poly, t, CA, CB);
    emit_pair(inter, aa[i], aa[j], i, j, mask, words, wl, wl_count);
  }
}

// ---------------- K3: greedy sweep (sparse; LDS mask prefetch r10) --------
__global__ void __launch_bounds__(1024) nms_sweep(
    const unsigned long long* __restrict__ mask, const int* __restrict__ order,
    const unsigned int* __restrict__ wl, const int* __restrict__ wl_count,
    int* __restrict__ out, int N, int words, int topn) {
  __shared__ unsigned long long sup_sh[64];
  __shared__ int prefix[65];
  __shared__ int h[2048], dst[2048];
  __shared__ int wtot[16];
  __shared__ unsigned int keys[WL_LDS_CAP];
  __shared__ unsigned long long vals[WL_LDS_CAP];  // 32 KB
  int t = threadIdx.x;
  int lane = t & 63;
  int wid = t >> 6;
  int n_wl = *wl_count;
  bool sparse = (words <= 32) && (N <= 2048) && (n_wl <= WL_LDS_CAP);

  if (sparse) {
    if (t < 64) sup_sh[t] = 0ull;
    for (int k = t; k < N; k += 1024) h[k] = 0;
    __syncthreads();
    // histogram + parallel gather of mask words (held in registers)
    unsigned lk[WL_LDS_CAP / 1024];
    unsigned long long lv[WL_LDS_CAP / 1024];
    int ne = 0;
    for (int e = t; e < n_wl; e += 1024) {
      unsigned key = wl[e];
      lk[ne] = key;
      lv[ne] = mask[(size_t)(key >> 6) * words + (key & 63)];
      atomicAdd(&h[key >> 6], 1);
      ++ne;
    }
    __syncthreads();
    int a = (2 * t < N) ? h[2 * t] : 0;
    int b = (2 * t + 1 < N) ? h[2 * t + 1] : 0;
    int s = a + b;
    for (int d = 1; d < 64; d <<= 1) {
      int v = __shfl_up(s, d);
      if (lane >= d) s += v;
    }
    if (lane == 63) wtot[wid] = s;
    __syncthreads();
    if (wid == 0) {
      int w = (lane < 16) ? wtot[lane] : 0;
      for (int d = 1; d < 16; d <<= 1) {
        int v = __shfl_up(w, d);
        if (lane >= d) w += v;
      }
      if (lane < 16) wtot[lane] = w;
    }
    __syncthreads();
    int base = (wid ? wtot[wid - 1] : 0) + (s - (a + b));
    if (2 * t < N) dst[2 * t] = base;
    if (2 * t + 1 < N) dst[2 * t + 1] = base + a;
    __syncthreads();
    for (int ii = 0; ii < ne; ++ii) {
      int pos = atomicAdd(&dst[lk[ii] >> 6], 1);
      keys[pos] = lk[ii];
      vals[pos] = lv[ii];
    }
    __syncthreads();
    if (t < 64) {
      unsigned long long sup = 0ull;
      unsigned long long supg = 0ull;
      int cur_g = -1;
      int chunks = (n_wl + 63) >> 6;
      for (int c = 0; c < chunks; ++c) {
        int idx = (c << 6) + lane;
        unsigned key = (idx < n_wl) ? keys[idx] : 0u;
        unsigned long long val = (idx < n_wl) ? vals[idx] : 0ull;
        int lim = n_wl - (c << 6);
        if (lim > 64) lim = 64;
        for (int e = 0; e < lim; ++e) {
          unsigned k2 = __shfl(key, e);
          unsigned long long v2 = __shfl(val, e);
          int r = k2 >> 6, w = k2 & 63, g = r >> 6;
          if (g != cur_g) {
            supg = __shfl(sup, g);
            cur_g = g;
          }
          bool kept = !((supg >> (r & 63)) & 1ull);
          if (kept) {
            if (lane == w) sup |= v2;
            if (w == g) supg |= v2;
          }
        }
      }
      sup_sh[lane] = (lane < words) ? sup : 0ull;
    }
    __syncthreads();
  } else {
    if (t < 64) sup_sh[t] = 0ull;
    __syncthreads();
    int rstride = 1024 / words;
    int w2 = t % words;
    int rl0 = t / words;
    for (int g = 0; g < words; ++g) {
      if (wid == 0) {
        int r = g * 64 + lane;
        unsigned long long d = (r < N) ? mask[(size_t)r * words + g] : 0ull;
        unsigned long long supmask = sup_sh[g];
        for (int lp = 0; lp < 64; ++lp) {
          if (!((supmask >> lp) & 1ull)) supmask |= __shfl(d, lp);
        }
        if (lane == 0) sup_sh[g] = supmask;
      }
      __syncthreads();
      unsigned long long supg = sup_sh[g];
      if (w2 > g) {
        unsigned long long acc = 0ull;
        for (int rl = rl0; rl < 64; rl += rstride) {
          if (!((supg >> rl) & 1ull)) {
            int r = g * 64 + rl;
            if (r < N) acc |= mask[(size_t)r * words + w2];
          }
        }
        if (acc) atomicOr(&sup_sh[w2], acc);
      }
      __syncthreads();
    }
  }

  if (t == 0) {
    int acc = 0;
    for (int w = 0; w < words; ++w) {
      prefix[w] = acc;
      int hi = N - w * 64;
      unsigned long long keptw = ~sup_sh[w];
      if (hi < 64) keptw &= (1ull << hi) - 1ull;
      acc += __popcll(keptw);
    }
    prefix[words] = acc;
  }
  __syncthreads();
  int total = prefix[words];
  for (int i = t; i < N; i += 1024) {
    int w = i >> 6, bb = i & 63;
    if (!((sup_sh[w] >> bb) & 1ull)) {
      int pos = prefix[w] + __popcll(~sup_sh[w] & ((1ull << bb) - 1ull));
      if (pos < topn) out[pos] = order[i];
    }
  }
  for (int k = total + t; k < topn; k += 1024) out[k] = -1;
}

// =================== fallback path (N > 2048) =============================
__device__ float clip_inter_area_reg(const float* __restrict__ A,
                                     const float* __restrict__ B) {
#pragma clang fp contract(off)
  float Px[8], Py[8], Qx[8], Qy[8];
  for (int k = 0; k < 4; ++k) {
    Px[k] = A[2 * k];
    Py[k] = A[2 * k + 1];
  }
  int cnt = 4;
  for (int e = 0; e < 4; ++e) {
    float ax = B[2 * e], ay = B[2 * e + 1];
    int e2 = (e + 1) & 3;
    float bx = B[2 * e2], by = B[2 * e2 + 1];
    float ex = bx - ax, ey = by - ay;
    int ncnt = 0;
    for (int k = 0; k < cnt; ++k) {
      int kn = (k + 1 < cnt) ? k + 1 : 0;
      float dc = ex * (Py[k] - ay) - ey * (Px[k] - ax);
      float dn = ex * (Py[kn] - ay) - ey * (Px[kn] - ax);
      bool ic = (dc >= 0.0f), inx = (dn >= 0.0f);
      if (ic) {
        if (ncnt < 8) {
          Qx[ncnt] = Px[k];
          Qy[ncnt] = Py[k];
        }
        ++ncnt;
      }
      if (ic != inx) {
        float denom = dc - dn;
        float tp = (fabsf(denom) > 1e-12f) ? (dc / denom) : 0.0f;
        if (ncnt < 8) {
          Qx[ncnt] = Px[k] + tp * (Px[kn] - Px[k]);
          Qy[ncnt] = Py[k] + tp * (Py[kn] - Py[k]);
        }
        ++ncnt;
      }
    }
    cnt = ncnt > 8 ? 8 : ncnt;
    for (int k = 0; k < cnt; ++k) {
      Px[k] = Qx[k];
      Py[k] = Qy[k];
    }
  }
  float area = 0.0f;
  for (int k = 0; k < cnt; ++k) {
    int kn = (k + 1 < cnt) ? k + 1 : 0;
    area += Px[k] * Py[kn] - Px[kn] * Py[k];
  }
  return fmaxf(0.5f * area, 0.0f);
}

__global__ void rank_kernel_fb(const float* __restrict__ scores,
                               int* __restrict__ order, int N) {
  int i = blockIdx.x * blockDim.x + threadIdx.x;
  if (i >= N) return;
  float si = scores[i];
  int r = 0;
  for (int j = 0; j < N; ++j) {
    float sj = scores[j];
    if (sj > si || (sj == si && j < i)) ++r;
  }
  order[r] = i;
}

__global__ void prep_kernel_fb(const float* __restrict__ boxes,
                               const int* __restrict__ order,
                               float* __restrict__ sbox, int N) {
#pragma clang fp contract(off)
  int i = blockIdx.x * blockDim.x + threadIdx.x;
  if (i >= N) return;
  int bx = order[i];
  const float* bp = boxes + 5 * bx;
  float w = bp[2], h = bp[3];
  float* o = sbox + (size_t)i * 12;
  make_corners(bp, o);
  o[8] = bp[0];
  o[9] = bp[1];
  o[10] = 0.5f * sqrtf(w * w + h * h);
  o[11] = w * h;
}

__global__ void iou_direct_kernel(const float* __restrict__ sbox,
                                  unsigned long long* __restrict__ mask, int N,
                                  int words) {
#pragma clang fp contract(off)
  int j = blockIdx.x * blockDim.x + threadIdx.x;
  int i = blockIdx.y;
  if (j >= N || j <= i) return;
  const float* A = sbox + (size_t)i * 12;
  const float* B = sbox + (size_t)j * 12;
  float ddx = B[8] - A[8], ddy = B[9] - A[9];
  float rs = A[10] + B[10];
  if (ddx * ddx + ddy * ddy > rs * rs) return;
  float mn = fminf(A[11], B[11]), mx = fmaxf(A[11], B[11]);
  if (!(mn > 0.699f * mx)) return;
  float inter = clip_inter_area_reg(A, B);
  float uni = A[11] + B[11] - inter;
  float iou = inter / fmaxf(uni, 1e-9f);
  if (iou > 0.7f)
    atomicOr(&mask[(size_t)i * words + (j >> 6)], 1ull << (j & 63));
}

__global__ void __launch_bounds__(1024) nms_sweep_fb(
    const unsigned long long* __restrict__ mask, const int* __restrict__ order,
    int* __restrict__ out, int N, int words, int topn) {
  __shared__ unsigned long long sup[64];
  __shared__ int prefix[65];
  int t = threadIdx.x;
  int lane = t & 63;
  int wave = t >> 6;
  if (t < words) sup[t] = 0ull;
  __syncthreads();
  int rstride = 1024 / words;
  int w2 = t % words;
  int rl0 = t / words;
  for (int g = 0; g < words; ++g) {
    if (wave == 0) {
      int r = g * 64 + lane;
      unsigned long long d = (r < N) ? mask[(size_t)r * words + g] : 0ull;
      unsigned long long supmask = sup[g];
      for (int lp = 0; lp < 64; ++lp) {
        if (!((supmask >> lp) & 1ull)) supmask |= __shfl(d, lp);
      }
      if (lane == 0) sup[g] = supmask;
    }
    __syncthreads();
    unsigned long long supg = sup[g];
    if (w2 > g) {
      unsigned long long acc = 0ull;
      for (int rl = rl0; rl < 64; rl += rstride) {
        if (!((supg >> rl) & 1ull)) {
          int r = g * 64 + rl;
          if (r < N) acc |= mask[(size_t)r * words + w2];
        }
      }
      if (acc) atomicOr(&sup[w2], acc);
    }
    __syncthreads();
  }
  if (t == 0) {
    int acc = 0;
    for (int w = 0; w < words; ++w) {
      prefix[w] = acc;
      int hi = N - w * 64;
      unsigned long long keptw = ~sup[w];
      if (hi < 64) keptw &= (1ull << hi) - 1ull;
      acc += __popcll(keptw);
    }
    prefix[words] = acc;
  }
  __syncthreads();
  int total = prefix[words];
  for (int i = t; i < N; i += 1024) {
    int w = i >> 6, bb = i & 63;
    if (!((sup[w] >> bb) & 1ull)) {
      int pos = prefix[w] + __popcll(~sup[w] & ((1ull << bb) - 1ull));
      if (pos < topn) out[pos] = order[i];
    }
  }
  for (int k = total + t; k < topn; k += 1024) out[k] = -1;
}

extern "C" void kernel_launch(void* const* d_in, const int* in_sizes, int n_in,
                              void* d_out, int out_size, void* d_ws,
                              size_t ws_size, hipStream_t stream) {
  const float* boxes = (const float*)d_in[0];
  const float* scores = (const float*)d_in[1];
  int N = in_sizes[1];
  int words = (N + 63) / 64;

  char* ws = (char*)d_ws;
  size_t off = 0;
  unsigned long long* mask = (unsigned long long*)(ws + off);
  off += (size_t)N * words * sizeof(unsigned long long);
  float4* geo = (float4*)(ws + off);
  off += (size_t)N * sizeof(float4);
  int* order = (int*)(ws + off);
  off += (size_t)N * sizeof(int);
  int* wl_count = (int*)(ws + off);
  off += 16;
  unsigned int* wl = (unsigned int*)(ws + off);
  off += (size_t)WL_G_CAP * sizeof(unsigned int);
  float* sbox = (float*)(ws + off);  // fallback only
  off += (size_t)N * 12 * sizeof(float);

  int topn = out_size;
  int* out = (int*)d_out;

  if (N <= 2048) {
    int rb = (N + 7) / 8;
    rank_order<<<rb, 256, 0, stream>>>(boxes, scores, order, geo, mask, words,
                                       wl_count, N);
    circle_clip<<<512, CF_T, 0, stream>>>(boxes, order, geo, mask, words, wl,
                                          wl_count, N);
    nms_sweep<<<1, 1024, 0, stream>>>(mask, order, wl, wl_count, out, N, words,
                                      topn);
  } else {
    int nb = (N + 255) / 256;
    hipMemsetAsync(mask, 0, (size_t)N * words * 8, stream);
    rank_kernel_fb<<<nb, 256, 0, stream>>>(scores, order, N);
    prep_kernel_fb<<<nb, 256, 0, stream>>>(boxes, order, sbox, N);
    dim3 grid(nb, N);
    iou_direct_kernel<<<grid, 256, 0, stream>>>(sbox, mask, N, words);
    nms_sweep_fb<<<1, 1024, 0, stream>>>(mask, order, out, N, words, topn);
  }
}